// Round 5
// baseline (1304.704 us; speedup 1.0000x reference)
//
#include <hip/hip_runtime.h>
#include <stdint.h>

// SAINT encoder: B=32 S=512 D=512 H=8 DH=64 F=2048 L=4
#define B_ 32
#define S_ 512
#define D_ 512
#define H_ 8
#define F_ 2048
#define L_ 4
#define DH_ 64
#define M_ (B_*S_)

typedef unsigned short u16;
typedef float f32x4 __attribute__((ext_vector_type(4)));
typedef short bf16x8 __attribute__((ext_vector_type(8)));

__device__ __forceinline__ u16 f2b(float f) {
  unsigned u = __float_as_uint(f);
  u += 0x7FFFu + ((u >> 16) & 1u);
  return (u16)(u >> 16);
}
__device__ __forceinline__ float b2f(u16 u) {
  return __uint_as_float((unsigned)u << 16);
}
__device__ __forceinline__ void gld16(const void* g, void* l) {
  __builtin_amdgcn_global_load_lds((__attribute__((address_space(1))) void*)(void*)g,
                                   (__attribute__((address_space(3))) void*)l, 16, 0, 0);
}
__device__ __forceinline__ f32x4 mfma16(bf16x8 a, bf16x8 b, f32x4 c) {
  return __builtin_amdgcn_mfma_f32_16x16x32_bf16(a, b, c, 0, 0, 0);
}
__device__ __forceinline__ float gelu_exact(float x) {
  return 0.5f * x * (1.0f + erff(x * 0.70710678118654752f));
}

// ---------------- weight transpose + bf16: W[R][C] f32 -> WT[C][R] bf16 -----------
__global__ __launch_bounds__(256) void transpose_w(const float* __restrict__ in,
                                                   u16* __restrict__ out, int R, int C) {
  __shared__ float tile[32][33];
  const int l = blockIdx.z;
  in  += (size_t)l * R * C;
  out += (size_t)l * R * C;
  const int c0 = blockIdx.x * 32, r0 = blockIdx.y * 32;
  const int tx = threadIdx.x, ty = threadIdx.y;
#pragma unroll
  for (int k = 0; k < 4; k++)
    tile[ty + 8*k][tx] = in[(size_t)(r0 + ty + 8*k) * C + c0 + tx];
  __syncthreads();
#pragma unroll
  for (int k = 0; k < 4; k++)
    out[(size_t)(c0 + ty + 8*k) * R + r0 + tx] = f2b(tile[tx][ty + 8*k]);
}

// ---------------- x init ----------------------------------------------------------
__global__ __launch_bounds__(256) void prep_x(const float* __restrict__ h,
                                              float* __restrict__ x, u16* __restrict__ xb) {
  int i = blockIdx.x * 256 + threadIdx.x;
  float4 v = ((const float4*)h)[i];
  ((float4*)x)[i] = v;
  ushort4 u; u.x = f2b(v.x); u.y = f2b(v.y); u.z = f2b(v.z); u.w = f2b(v.w);
  ((ushort4*)xb)[i] = u;
}

// ---------------- pbias f32 -> bf16 -----------------------------------------------
__global__ __launch_bounds__(256) void prep_pb(const float* __restrict__ pb,
                                               u16* __restrict__ out) {
  int i = blockIdx.x * 256 + threadIdx.x;
  float4 v = ((const float4*)pb)[i];
  ushort4 o; o.x = f2b(v.x); o.y = f2b(v.y); o.z = f2b(v.z); o.w = f2b(v.w);
  ((ushort4*)out)[i] = o;
}

// ---------------- GEMM: C[M,N] = A[M,K] * BT[N,K]^T, 128x128 tile, BK=64 ----------
// R3 staging restored (contiguous B rows; nmap permutation regressed Wi 71->107us,
// scattered 4-row-stride bases stall the staging stream — reverted).
// epi: 0 = bf16 (+bias); 1 = bf16 (+bias + f32 residual); 2 = bf16 gelu(+bias);
//      3 = bf16 transposed V layout [B,H,DH,S] (+bias), r-packed ushort4 stores
__device__ __forceinline__ void gemm_core(
    const u16* __restrict__ A, const u16* __restrict__ BT,
    const int N, const int K,
    const float* __restrict__ bias, const float* __restrict__ resf,
    u16* __restrict__ outb, const int epi)
{
  __shared__ u16 As[128*64];
  __shared__ u16 Bs[128*64];
  const int tid = threadIdx.x;
  const int wid = tid >> 6, lane = tid & 63;
  const int wm = (wid >> 1) * 64, wn = (wid & 1) * 64;
  const int lr = lane & 15, quad = lane >> 4;
  const int m0 = blockIdx.x * 128, n0 = blockIdx.y * 128;
  const int l7 = lane & 7, l3 = lane >> 3;
  const int cc = (l7 ^ l3) * 8;          // swizzled staged col offset (u16)
  const int f8 = lr & 7;                 // read swizzle factor

  f32x4 acc[4][4];
#pragma unroll
  for (int i = 0; i < 4; i++)
#pragma unroll
    for (int j = 0; j < 4; j++) acc[i][j] = (f32x4){0.f, 0.f, 0.f, 0.f};

  const u16* Ag = A  + (size_t)(m0 + wid*16 + l3)*K + cc;
  const u16* Bg = BT + (size_t)(n0 + wid*16 + l3)*K + cc;
  u16* AsW = As + wid*1024;
  u16* BsW = Bs + wid*1024;

  for (int k0 = 0; k0 < K; k0 += 64) {
    gld16(Ag + k0,                 AsW);
    gld16(Ag + (size_t)8*K + k0,   AsW + 512);
    gld16(Ag + (size_t)64*K + k0,  AsW + 4096);
    gld16(Ag + (size_t)72*K + k0,  AsW + 4608);
    gld16(Bg + k0,                 BsW);
    gld16(Bg + (size_t)8*K + k0,   BsW + 512);
    gld16(Bg + (size_t)64*K + k0,  BsW + 4096);
    gld16(Bg + (size_t)72*K + k0,  BsW + 4608);
    __syncthreads();
#pragma unroll
    for (int kh = 0; kh < 2; kh++) {
      bf16x8 af[4], bfr[4];
#pragma unroll
      for (int i = 0; i < 4; i++)
        af[i]  = *(const bf16x8*)(As + (wm + i*16 + lr)*64 + (((kh*4 + quad) ^ f8) * 8));
#pragma unroll
      for (int j = 0; j < 4; j++)
        bfr[j] = *(const bf16x8*)(Bs + (wn + j*16 + lr)*64 + (((kh*4 + quad) ^ f8) * 8));
#pragma unroll
      for (int i = 0; i < 4; i++)
#pragma unroll
        for (int j = 0; j < 4; j++)
          acc[i][j] = mfma16(af[i], bfr[j], acc[i][j]);
    }
    __syncthreads();
  }

  // bias for this lane's 4 j-columns
  float bn[4];
#pragma unroll
  for (int j = 0; j < 4; j++) bn[j] = bias[n0 + wn + j*16 + lr];

  if (epi == 3) {
#pragma unroll
    for (int i = 0; i < 4; i++) {
      const int m = m0 + wm + i*16 + quad*4;     // sr base; r spans +0..3
      const int bb_ = m >> 9, sr = m & 511;
#pragma unroll
      for (int j = 0; j < 4; j++) {
        const int n = n0 + wn + j*16 + lr;
        const int hh = n >> 6, dd = n & 63;
        ushort4 o;
        o.x = f2b(acc[i][j][0] + bn[j]);
        o.y = f2b(acc[i][j][1] + bn[j]);
        o.z = f2b(acc[i][j][2] + bn[j]);
        o.w = f2b(acc[i][j][3] + bn[j]);
        *(ushort4*)(outb + (((size_t)((bb_*H_ + hh)*DH_ + dd)) << 9) + sr) = o;
      }
    }
  } else {
#pragma unroll
    for (int i = 0; i < 4; i++) {
#pragma unroll
      for (int r = 0; r < 4; r++) {
        const size_t m = (size_t)(m0 + wm + i*16 + quad*4 + r);
#pragma unroll
        for (int j = 0; j < 4; j++) {           // j innermost: adjacent 32B stores/row
          const int n = n0 + wn + j*16 + lr;
          float v = acc[i][j][r] + bn[j];
          if (epi == 0)      outb[m*N + n] = f2b(v);
          else if (epi == 1) outb[m*N + n] = f2b(v + resf[m*N + n]);
          else               outb[m*N + n] = f2b(gelu_exact(v));
        }
      }
    }
  }
}

__global__ __launch_bounds__(256) void gemm_kernel(
    const u16* A, const u16* BT, int N, int K,
    const float* bias, const float* resf, u16* outb, int epi)
{
  gemm_core(A, BT, N, K, bias, resf, outb, epi);
}

__global__ __launch_bounds__(256) void gemm_qkv_kernel(
    const u16* A, const u16* BTq, size_t zstride, int K,
    const float* b0, const float* b1, const float* b2,
    u16* out0, u16* out1, u16* out2)
{
  const int z = blockIdx.z;
  const u16* BT = BTq + (size_t)z * zstride;
  const float* bias = (z == 0) ? b0 : (z == 1) ? b1 : b2;
  u16* outb = (z == 0) ? out0 : (z == 1) ? out1 : out2;
  gemm_core(A, BT, 512, K, bias, nullptr, outb, (z == 2) ? 3 : 0);
}

// ---------------- LayerNorm: bf16 in; bf16 out + optional f32 out -----------------
__global__ __launch_bounds__(256) void ln_kernel(
    const u16* __restrict__ y, const float* __restrict__ g, const float* __restrict__ bta,
    float* __restrict__ outf, u16* __restrict__ outb)
{
  const int lane = threadIdx.x & 63;
  const int row = blockIdx.x*4 + (threadIdx.x >> 6);
  const u16* yr = y + (size_t)row*D_ + lane*8;
  ushort4 a0 = *(const ushort4*)yr;
  ushort4 a1 = *(const ushort4*)(yr + 4);
  float v[8] = {b2f(a0.x), b2f(a0.y), b2f(a0.z), b2f(a0.w),
                b2f(a1.x), b2f(a1.y), b2f(a1.z), b2f(a1.w)};
  float s = 0.f;
#pragma unroll
  for (int e = 0; e < 8; e++) s += v[e];
#pragma unroll
  for (int m = 1; m < 64; m <<= 1) s += __shfl_xor(s, m);
  const float mu = s * (1.0f/512.0f);
  float q = 0.f;
#pragma unroll
  for (int e = 0; e < 8; e++) { float d = v[e] - mu; q += d*d; }
#pragma unroll
  for (int m = 1; m < 64; m <<= 1) q += __shfl_xor(q, m);
  const float rs = rsqrtf(q * (1.0f/512.0f) + 1e-12f);
  float4 g0 = *(const float4*)(g + lane*8);
  float4 g1 = *(const float4*)(g + lane*8 + 4);
  float4 b0 = *(const float4*)(bta + lane*8);
  float4 b1 = *(const float4*)(bta + lane*8 + 4);
  float gg[8] = {g0.x, g0.y, g0.z, g0.w, g1.x, g1.y, g1.z, g1.w};
  float bb[8] = {b0.x, b0.y, b0.z, b0.w, b1.x, b1.y, b1.z, b1.w};
  float o[8];
#pragma unroll
  for (int e = 0; e < 8; e++) o[e] = (v[e] - mu) * rs * gg[e] + bb[e];
  if (outf) {
    float4 w0 = {o[0], o[1], o[2], o[3]}, w1 = {o[4], o[5], o[6], o[7]};
    *(float4*)(outf + (size_t)row*D_ + lane*8)     = w0;
    *(float4*)(outf + (size_t)row*D_ + lane*8 + 4) = w1;
  }
  ushort4 u0 = {f2b(o[0]), f2b(o[1]), f2b(o[2]), f2b(o[3])};
  ushort4 u1 = {f2b(o[4]), f2b(o[5]), f2b(o[6]), f2b(o[7])};
  *(ushort4*)(outb + (size_t)row*D_ + lane*8)     = u0;
  *(ushort4*)(outb + (size_t)row*D_ + lane*8 + 4) = u1;
}

// ---------------- flash attention; inline lag-scale; grid (b, it, h) --------------
__global__ __launch_bounds__(256, 4) void attn_kernel(
    const u16* __restrict__ qb, const u16* __restrict__ kb, const u16* __restrict__ vt,
    const u16* __restrict__ pb16, const int* __restrict__ ts, u16* __restrict__ cb)
{
  __shared__ u16 QPs[64*64];                 // Q tile; wave's 16-row slice reused as P
  __shared__ u16 Ks[64*64], Vs[64*64], PBs[64*64];
  __shared__ float Tif[64], Tjf[64];
  const int b = blockIdx.x, it = blockIdx.y, h = blockIdx.z;
  const int i0 = it * 64;
  const int tid = threadIdx.x, wid = tid >> 6, lane = tid & 63;
  const int lr = lane & 15, quad = lane >> 4;
  const int l7 = lane & 7, l3 = lane >> 3;
  const int cc = (l7 ^ l3) * 8;
  const int f8 = lr & 7;
  const int rr = wid*8 + l3;

  const u16* qg  = qb + ((size_t)(b*S_ + i0))*D_ + h*DH_;
  const u16* kg  = kb + ((size_t)b*S_)*D_ + h*DH_;
  const u16* vg  = vt + ((size_t)(b*H_ + h)*DH_)*S_;
  const u16* pbg = pb16 + ((size_t)(h*S_ + i0))*S_;

  gld16(qg + (size_t)rr*D_ + cc,        QPs + wid*512);
  gld16(qg + (size_t)(rr+32)*D_ + cc,   QPs + 2048 + wid*512);
  if (tid < 64) Tif[tid] = (float)ts[b*S_ + i0 + tid] * (1.0f/60000.0f);
  __syncthreads();

  bf16x8 aq0 = *(const bf16x8*)(QPs + (wid*16 + lr)*64 + ((quad ^ f8) * 8));
  bf16x8 aq1 = *(const bf16x8*)(QPs + (wid*16 + lr)*64 + (((quad ^ f8) ^ 4) * 8));
  u16* Pw = QPs + wid*1024;

  float tis[4];
#pragma unroll
  for (int r = 0; r < 4; r++) tis[r] = Tif[wid*16 + quad*4 + r];

  f32x4 O[4]; float lacc[4];
#pragma unroll
  for (int dt = 0; dt < 4; dt++) O[dt] = (f32x4){0.f, 0.f, 0.f, 0.f};
#pragma unroll
  for (int r = 0; r < 4; r++) lacc[r] = 0.f;
  const int lrh = lr >> 3;

  for (int t8 = 0; t8 < 8; t8++) {
    const int j0 = t8 * 64;
    gld16(kg + (size_t)(j0+rr)*D_ + cc,      Ks + wid*512);
    gld16(kg + (size_t)(j0+rr+32)*D_ + cc,   Ks + 2048 + wid*512);
    gld16(vg + (size_t)rr*S_ + j0 + cc,      Vs + wid*512);
    gld16(vg + (size_t)(rr+32)*S_ + j0 + cc, Vs + 2048 + wid*512);
    gld16(pbg + (size_t)rr*S_ + j0 + cc,      PBs + wid*512);
    gld16(pbg + (size_t)(rr+32)*S_ + j0 + cc, PBs + 2048 + wid*512);
    if (tid < 64) Tjf[tid] = (float)ts[b*S_ + j0 + tid] * (1.0f/60000.0f);
    __syncthreads();

    f32x4 s[4];
#pragma unroll
    for (int jt = 0; jt < 4; jt++) {
      const u16* kr = Ks + (jt*16 + lr)*64;
      bf16x8 bk0 = *(const bf16x8*)(kr + ((quad ^ f8) * 8));
      bf16x8 bk1 = *(const bf16x8*)(kr + (((quad ^ f8) ^ 4) * 8));
      f32x4 z = (f32x4){0.f, 0.f, 0.f, 0.f};
      z = mfma16(aq0, bk0, z);
      z = mfma16(aq1, bk1, z);
      s[jt] = z;
    }
#pragma unroll
    for (int r = 0; r < 4; r++) {
      const int rowl = quad*4 + r;
      const int rbase = (wid*16 + rowl) * 64;
      const int r7 = rowl & 7;
      float pa = 0.f;
#pragma unroll
      for (int jt = 0; jt < 4; jt++) {
        const int idx = (((jt*2 + lrh) ^ r7) * 8) + l7;
        float lag = fmaxf(tis[r] - Tjf[idx], 0.0f);
        float inv = (lag + 1.0f) * __builtin_amdgcn_rcpf(fmaf(lag, 9.0f, 8.0f));
        float pbf = b2f(PBs[rbase + idx]);
        float p = __expf(fmaf(s[jt][r], inv, pbf));
        pa += p;
        Pw[rowl*64 + idx] = f2b(p);
      }
      lacc[r] += pa;
    }
    bf16x8 ap0 = *(const bf16x8*)(Pw + lr*64 + ((quad ^ f8) * 8));
    bf16x8 ap1 = *(const bf16x8*)(Pw + lr*64 + (((quad ^ f8) ^ 4) * 8));
#pragma unroll
    for (int dt = 0; dt < 4; dt++) {
      const u16* vr = Vs + (dt*16 + lr)*64;
      bf16x8 bv0 = *(const bf16x8*)(vr + ((quad ^ f8) * 8));
      bf16x8 bv1 = *(const bf16x8*)(vr + (((quad ^ f8) ^ 4) * 8));
      O[dt] = mfma16(ap0, bv0, O[dt]);
      O[dt] = mfma16(ap1, bv1, O[dt]);
    }
    __syncthreads();
  }

#pragma unroll
  for (int r = 0; r < 4; r++) {
    float sum = lacc[r];
#pragma unroll
    for (int m = 1; m < 16; m <<= 1) sum += __shfl_xor(sum, m);
    const float inv = __builtin_amdgcn_rcpf(sum);
    const size_t row = (size_t)(b*S_ + i0 + wid*16 + quad*4 + r);
#pragma unroll
    for (int dt = 0; dt < 4; dt++)
      cb[row*D_ + h*DH_ + dt*16 + lr] = f2b(O[dt][r] * inv);
  }
}

// ---------------- orchestration ---------------------------------------------------
extern "C" void kernel_launch(void* const* d_in, const int* in_sizes, int n_in,
                              void* d_out, int out_size, void* d_ws, size_t ws_size,
                              hipStream_t stream)
{
  const float* hidden = (const float*)d_in[0];
  const float* pbias  = (const float*)d_in[1];
  const int*   ts     = (const int*)d_in[2];
  const float* Wq = (const float*)d_in[3];   const float* bq  = (const float*)d_in[4];
  const float* Wk = (const float*)d_in[5];   const float* bk  = (const float*)d_in[6];
  const float* Wv = (const float*)d_in[7];   const float* bv  = (const float*)d_in[8];
  const float* Wo = (const float*)d_in[9];   const float* bo  = (const float*)d_in[10];
  const float* l1g = (const float*)d_in[11]; const float* l1b = (const float*)d_in[12];
  const float* Wi = (const float*)d_in[13];  const float* bi  = (const float*)d_in[14];
  const float* Wf = (const float*)d_in[15];  const float* bfw = (const float*)d_in[16];
  const float* l2g = (const float*)d_in[17]; const float* l2b = (const float*)d_in[18];

  char* w = (char*)d_ws;
  u16* xb    = (u16*)w; w += (size_t)M_*D_*2;
  u16* qb    = (u16*)w; w += (size_t)M_*D_*2;
  u16* kbuf  = (u16*)w; w += (size_t)M_*D_*2;
  u16* vtw   = (u16*)w; w += (size_t)M_*D_*2;
  u16* cbuf  = (u16*)w; w += (size_t)M_*D_*2;
  u16* attnb = (u16*)w; w += (size_t)M_*D_*2;
  u16* yb    = (u16*)w; w += (size_t)M_*D_*2;
  float* attnf = (float*)w; w += (size_t)M_*D_*4;
  u16* WqkvT = (u16*)w; w += (size_t)3*L_*D_*D_*2;
  u16* WoT   = (u16*)w; w += (size_t)L_*D_*D_*2;
  u16* WiT   = (u16*)w; w += (size_t)L_*D_*F_*2;
  u16* WfT   = (u16*)w; w += (size_t)L_*F_*D_*2;
  u16* pbb   = (u16*)w; w += (size_t)H_*S_*S_*2;
  u16* hb    = qb;   // alias: qb..cbuf = M_*F_ bf16; lifetimes disjoint

  float* x = (float*)d_out;

  const size_t WD = (size_t)D_*D_;
  const size_t WF = (size_t)D_*F_;
  dim3 tb(32, 8);

  transpose_w<<<dim3(16,16,L_), tb, 0, stream>>>(Wq, WqkvT,           D_, D_);
  transpose_w<<<dim3(16,16,L_), tb, 0, stream>>>(Wk, WqkvT + L_*WD,   D_, D_);
  transpose_w<<<dim3(16,16,L_), tb, 0, stream>>>(Wv, WqkvT + 2*L_*WD, D_, D_);
  transpose_w<<<dim3(16,16,L_), tb, 0, stream>>>(Wo, WoT,             D_, D_);
  transpose_w<<<dim3(64,16,L_), tb, 0, stream>>>(Wi, WiT,             D_, F_);
  transpose_w<<<dim3(16,64,L_), tb, 0, stream>>>(Wf, WfT,             F_, D_);
  prep_x<<<dim3(8192), dim3(256), 0, stream>>>(hidden, x, xb);
  prep_pb<<<dim3(H_*S_*S_/1024), dim3(256), 0, stream>>>(pbias, pbb);

  for (int l = 0; l < L_; l++) {
    gemm_qkv_kernel<<<dim3(128,4,3), dim3(256), 0, stream>>>(
        xb, WqkvT + l*WD, (size_t)L_*WD, D_,
        bq + l*D_, bk + l*D_, bv + l*D_, qb, kbuf, vtw);
    attn_kernel<<<dim3(B_,8,H_), dim3(256), 0, stream>>>(qb, kbuf, vtw, pbb, ts, cbuf);
    gemm_kernel<<<dim3(128,4), dim3(256), 0, stream>>>(
        cbuf, WoT + l*WD, D_, D_, bo + l*D_, x, yb, 1);
    ln_kernel<<<dim3(4096), dim3(256), 0, stream>>>(yb, l1g + l*D_, l1b + l*D_,
                                                    attnf, attnb);
    gemm_kernel<<<dim3(128,16), dim3(256), 0, stream>>>(
        attnb, WiT + l*WF, F_, D_, bi + l*F_, (const float*)nullptr, hb, 2);
    gemm_kernel<<<dim3(128,4), dim3(256), 0, stream>>>(
        hb, WfT + l*WF, D_, F_, bfw + l*D_, attnf, yb, 1);
    ln_kernel<<<dim3(4096), dim3(256), 0, stream>>>(yb, l2g + l*D_, l2b + l*D_, x, xb);
  }
}

// Round 6
// 1077.474 us; speedup vs baseline: 1.2109x; 1.2109x over previous
//
#include <hip/hip_runtime.h>
#include <stdint.h>

// SAINT encoder: B=32 S=512 D=512 H=8 DH=64 F=2048 L=4
#define B_ 32
#define S_ 512
#define D_ 512
#define H_ 8
#define F_ 2048
#define L_ 4
#define DH_ 64
#define M_ (B_*S_)

typedef unsigned short u16;
typedef float f32x4 __attribute__((ext_vector_type(4)));
typedef short bf16x8 __attribute__((ext_vector_type(8)));

__device__ __forceinline__ u16 f2b(float f) {
  unsigned u = __float_as_uint(f);
  u += 0x7FFFu + ((u >> 16) & 1u);
  return (u16)(u >> 16);
}
__device__ __forceinline__ float b2f(u16 u) {
  return __uint_as_float((unsigned)u << 16);
}
__device__ __forceinline__ void gld16(const void* g, void* l) {
  __builtin_amdgcn_global_load_lds((__attribute__((address_space(1))) void*)(void*)g,
                                   (__attribute__((address_space(3))) void*)l, 16, 0, 0);
}
__device__ __forceinline__ f32x4 mfma16(bf16x8 a, bf16x8 b, f32x4 c) {
  return __builtin_amdgcn_mfma_f32_16x16x32_bf16(a, b, c, 0, 0, 0);
}
// tanh-form GELU (max |err| ~3e-3 vs erf form; renormalized downstream by Wf+LN)
__device__ __forceinline__ float gelu_fast(float x) {
  float z = 0.7978845608028654f * fmaf(0.044715f * x, x * x, x);
  float e = __expf(2.0f * z);
  float t = 1.0f - 2.0f * __builtin_amdgcn_rcpf(e + 1.0f);   // tanh(z)
  return 0.5f * x * (1.0f + t);
}

// ---------------- weight transpose + bf16: W[R][C] f32 -> WT[C][R] bf16 -----------
__global__ __launch_bounds__(256) void transpose_w(const float* __restrict__ in,
                                                   u16* __restrict__ out, int R, int C) {
  __shared__ float tile[32][33];
  const int l = blockIdx.z;
  in  += (size_t)l * R * C;
  out += (size_t)l * R * C;
  const int c0 = blockIdx.x * 32, r0 = blockIdx.y * 32;
  const int tx = threadIdx.x, ty = threadIdx.y;
#pragma unroll
  for (int k = 0; k < 4; k++)
    tile[ty + 8*k][tx] = in[(size_t)(r0 + ty + 8*k) * C + c0 + tx];
  __syncthreads();
#pragma unroll
  for (int k = 0; k < 4; k++)
    out[(size_t)(c0 + ty + 8*k) * R + r0 + tx] = f2b(tile[tx][ty + 8*k]);
}

// ---------------- x init: bf16 only (f32 output written by final LN) --------------
__global__ __launch_bounds__(256) void prep_x(const float* __restrict__ h,
                                              u16* __restrict__ xb) {
  int i = blockIdx.x * 256 + threadIdx.x;
  float4 v = ((const float4*)h)[i];
  ushort4 u; u.x = f2b(v.x); u.y = f2b(v.y); u.z = f2b(v.z); u.w = f2b(v.w);
  ((ushort4*)xb)[i] = u;
}

// ---------------- pbias f32 -> bf16 -----------------------------------------------
__global__ __launch_bounds__(256) void prep_pb(const float* __restrict__ pb,
                                               u16* __restrict__ out) {
  int i = blockIdx.x * 256 + threadIdx.x;
  float4 v = ((const float4*)pb)[i];
  ushort4 o; o.x = f2b(v.x); o.y = f2b(v.y); o.z = f2b(v.z); o.w = f2b(v.w);
  ((ushort4*)out)[i] = o;
}

// ---------------- GEMM 128x128 tile, BK=64 (qkv / Wi) -----------------------------
// epi: 0 = bf16 (+bias); 2 = bf16 gelu(+bias); 3 = bf16 V-transposed [B,H,DH,S]
__device__ __forceinline__ void gemm_core(
    const u16* __restrict__ A, const u16* __restrict__ BT,
    const int N, const int K,
    const float* __restrict__ bias, u16* __restrict__ outb, const int epi)
{
  __shared__ u16 As[128*64];
  __shared__ u16 Bs[128*64];
  const int tid = threadIdx.x;
  const int wid = tid >> 6, lane = tid & 63;
  const int wm = (wid >> 1) * 64, wn = (wid & 1) * 64;
  const int lr = lane & 15, quad = lane >> 4;
  const int m0 = blockIdx.x * 128, n0 = blockIdx.y * 128;
  const int l7 = lane & 7, l3 = lane >> 3;
  const int cc = (l7 ^ l3) * 8;          // swizzled staged col offset (u16)
  const int f8 = lr & 7;                 // read swizzle factor

  f32x4 acc[4][4];
#pragma unroll
  for (int i = 0; i < 4; i++)
#pragma unroll
    for (int j = 0; j < 4; j++) acc[i][j] = (f32x4){0.f, 0.f, 0.f, 0.f};

  const u16* Ag = A  + (size_t)(m0 + wid*16 + l3)*K + cc;
  const u16* Bg = BT + (size_t)(n0 + wid*16 + l3)*K + cc;
  u16* AsW = As + wid*1024;
  u16* BsW = Bs + wid*1024;

  for (int k0 = 0; k0 < K; k0 += 64) {
    gld16(Ag + k0,                 AsW);
    gld16(Ag + (size_t)8*K + k0,   AsW + 512);
    gld16(Ag + (size_t)64*K + k0,  AsW + 4096);
    gld16(Ag + (size_t)72*K + k0,  AsW + 4608);
    gld16(Bg + k0,                 BsW);
    gld16(Bg + (size_t)8*K + k0,   BsW + 512);
    gld16(Bg + (size_t)64*K + k0,  BsW + 4096);
    gld16(Bg + (size_t)72*K + k0,  BsW + 4608);
    __syncthreads();
#pragma unroll
    for (int kh = 0; kh < 2; kh++) {
      bf16x8 af[4], bfr[4];
#pragma unroll
      for (int i = 0; i < 4; i++)
        af[i]  = *(const bf16x8*)(As + (wm + i*16 + lr)*64 + (((kh*4 + quad) ^ f8) * 8));
#pragma unroll
      for (int j = 0; j < 4; j++)
        bfr[j] = *(const bf16x8*)(Bs + (wn + j*16 + lr)*64 + (((kh*4 + quad) ^ f8) * 8));
#pragma unroll
      for (int i = 0; i < 4; i++)
#pragma unroll
        for (int j = 0; j < 4; j++)
          acc[i][j] = mfma16(af[i], bfr[j], acc[i][j]);
    }
    __syncthreads();
  }

  float bn[4];
#pragma unroll
  for (int j = 0; j < 4; j++) bn[j] = bias[n0 + wn + j*16 + lr];

  if (epi == 3) {
#pragma unroll
    for (int i = 0; i < 4; i++) {
      const int m = m0 + wm + i*16 + quad*4;     // sr base; r spans +0..3
      const int bb_ = m >> 9, sr = m & 511;
#pragma unroll
      for (int j = 0; j < 4; j++) {
        const int n = n0 + wn + j*16 + lr;
        const int hh = n >> 6, dd = n & 63;
        ushort4 o;
        o.x = f2b(acc[i][j][0] + bn[j]);
        o.y = f2b(acc[i][j][1] + bn[j]);
        o.z = f2b(acc[i][j][2] + bn[j]);
        o.w = f2b(acc[i][j][3] + bn[j]);
        *(ushort4*)(outb + (((size_t)((bb_*H_ + hh)*DH_ + dd)) << 9) + sr) = o;
      }
    }
  } else {
#pragma unroll
    for (int i = 0; i < 4; i++) {
#pragma unroll
      for (int r = 0; r < 4; r++) {
        const size_t m = (size_t)(m0 + wm + i*16 + quad*4 + r);
#pragma unroll
        for (int j = 0; j < 4; j++) {           // j innermost
          const int n = n0 + wn + j*16 + lr;
          float v = acc[i][j][r] + bn[j];
          if (epi == 2) v = gelu_fast(v);
          outb[m*N + n] = f2b(v);
        }
      }
    }
  }
}

__global__ __launch_bounds__(256) void gemm_kernel(
    const u16* A, const u16* BT, int N, int K,
    const float* bias, u16* outb, int epi)
{
  gemm_core(A, BT, N, K, bias, outb, epi);
}

__global__ __launch_bounds__(256) void gemm_qkv_kernel(
    const u16* A, const u16* BTq, size_t zstride, int K,
    const float* b0, const float* b1, const float* b2,
    u16* out0, u16* out1, u16* out2)
{
  const int z = blockIdx.z;
  const u16* BT = BTq + (size_t)z * zstride;
  const float* bias = (z == 0) ? b0 : (z == 1) ? b1 : b2;
  u16* outb = (z == 0) ? out0 : (z == 1) ? out1 : out2;
  gemm_core(A, BT, 512, K, bias, outb, (z == 2) ? 3 : 0);
}

// ---------------- GEMM 64x128 tile, BK=64 (Wo / Wf): f32 out + bias + bf16 res ----
// 1024 blocks for N=512 (4/CU), 24KB LDS (6 blocks/CU) -> latency-hiding for the
// occupancy-starved 512-block case measured in R5 (MfmaUtil 18%, VALUBusy 22%).
__global__ __launch_bounds__(256) void gemm64_kernel(
    const u16* __restrict__ A, const u16* __restrict__ BT,
    const int N, const int K,
    const float* __restrict__ bias, const u16* __restrict__ resb,
    float* __restrict__ outf)
{
  __shared__ u16 As[64*64];
  __shared__ u16 Bs[128*64];
  const int tid = threadIdx.x;
  const int wid = tid >> 6, lane = tid & 63;
  const int wm = (wid >> 1) * 32, wn = (wid & 1) * 64;
  const int lr = lane & 15, quad = lane >> 4;
  const int m0 = blockIdx.x * 64, n0 = blockIdx.y * 128;
  const int l7 = lane & 7, l3 = lane >> 3;
  const int cc = (l7 ^ l3) * 8;
  const int f8 = lr & 7;

  f32x4 acc[2][4];
#pragma unroll
  for (int i = 0; i < 2; i++)
#pragma unroll
    for (int j = 0; j < 4; j++) acc[i][j] = (f32x4){0.f, 0.f, 0.f, 0.f};

  const u16* Ag = A  + (size_t)(m0 + wid*8 + l3)*K + cc;
  const u16* Bg = BT + (size_t)(n0 + wid*16 + l3)*K + cc;
  u16* AsW = As + wid*512;
  u16* BsW = Bs + wid*1024;

  for (int k0 = 0; k0 < K; k0 += 64) {
    gld16(Ag + k0,                AsW);
    gld16(Ag + (size_t)32*K + k0, AsW + 2048);
    gld16(Bg + k0,                 BsW);
    gld16(Bg + (size_t)8*K + k0,   BsW + 512);
    gld16(Bg + (size_t)64*K + k0,  BsW + 4096);
    gld16(Bg + (size_t)72*K + k0,  BsW + 4608);
    __syncthreads();
#pragma unroll
    for (int kh = 0; kh < 2; kh++) {
      bf16x8 af[2], bfr[4];
#pragma unroll
      for (int i = 0; i < 2; i++)
        af[i]  = *(const bf16x8*)(As + (wm + i*16 + lr)*64 + (((kh*4 + quad) ^ f8) * 8));
#pragma unroll
      for (int j = 0; j < 4; j++)
        bfr[j] = *(const bf16x8*)(Bs + (wn + j*16 + lr)*64 + (((kh*4 + quad) ^ f8) * 8));
#pragma unroll
      for (int i = 0; i < 2; i++)
#pragma unroll
        for (int j = 0; j < 4; j++)
          acc[i][j] = mfma16(af[i], bfr[j], acc[i][j]);
    }
    __syncthreads();
  }

  float bn[4];
#pragma unroll
  for (int j = 0; j < 4; j++) bn[j] = bias[n0 + wn + j*16 + lr];

#pragma unroll
  for (int i = 0; i < 2; i++) {
#pragma unroll
    for (int r = 0; r < 4; r++) {
      const size_t m = (size_t)(m0 + wm + i*16 + quad*4 + r);
#pragma unroll
      for (int j = 0; j < 4; j++) {
        const int n = n0 + wn + j*16 + lr;
        outf[m*N + n] = acc[i][j][r] + bn[j] + b2f(resb[m*N + n]);
      }
    }
  }
}

// ---------------- LayerNorm: f32 in; bf16 out + optional f32 out ------------------
__global__ __launch_bounds__(256) void ln_kernel(
    const float* __restrict__ y, const float* __restrict__ g, const float* __restrict__ bta,
    float* __restrict__ outf, u16* __restrict__ outb)
{
  const int lane = threadIdx.x & 63;
  const int row = blockIdx.x*4 + (threadIdx.x >> 6);
  const float* yr = y + (size_t)row*D_ + lane*8;
  float4 a0 = *(const float4*)yr;
  float4 a1 = *(const float4*)(yr + 4);
  float v[8] = {a0.x, a0.y, a0.z, a0.w, a1.x, a1.y, a1.z, a1.w};
  float s = 0.f;
#pragma unroll
  for (int e = 0; e < 8; e++) s += v[e];
#pragma unroll
  for (int m = 1; m < 64; m <<= 1) s += __shfl_xor(s, m);
  const float mu = s * (1.0f/512.0f);
  float q = 0.f;
#pragma unroll
  for (int e = 0; e < 8; e++) { float d = v[e] - mu; q += d*d; }
#pragma unroll
  for (int m = 1; m < 64; m <<= 1) q += __shfl_xor(q, m);
  const float rs = rsqrtf(q * (1.0f/512.0f) + 1e-12f);
  float4 g0 = *(const float4*)(g + lane*8);
  float4 g1 = *(const float4*)(g + lane*8 + 4);
  float4 b0 = *(const float4*)(bta + lane*8);
  float4 b1 = *(const float4*)(bta + lane*8 + 4);
  float gg[8] = {g0.x, g0.y, g0.z, g0.w, g1.x, g1.y, g1.z, g1.w};
  float bb[8] = {b0.x, b0.y, b0.z, b0.w, b1.x, b1.y, b1.z, b1.w};
  float o[8];
#pragma unroll
  for (int e = 0; e < 8; e++) o[e] = (v[e] - mu) * rs * gg[e] + bb[e];
  if (outf) {
    float4 w0 = {o[0], o[1], o[2], o[3]}, w1 = {o[4], o[5], o[6], o[7]};
    *(float4*)(outf + (size_t)row*D_ + lane*8)     = w0;
    *(float4*)(outf + (size_t)row*D_ + lane*8 + 4) = w1;
  }
  ushort4 u0 = {f2b(o[0]), f2b(o[1]), f2b(o[2]), f2b(o[3])};
  ushort4 u1 = {f2b(o[4]), f2b(o[5]), f2b(o[6]), f2b(o[7])};
  *(ushort4*)(outb + (size_t)row*D_ + lane*8)     = u0;
  *(ushort4*)(outb + (size_t)row*D_ + lane*8 + 4) = u1;
}

// ---------------- flash attention; inline lag-scale; grid (b, it, h) --------------
__global__ __launch_bounds__(256, 4) void attn_kernel(
    const u16* __restrict__ qb, const u16* __restrict__ kb, const u16* __restrict__ vt,
    const u16* __restrict__ pb16, const int* __restrict__ ts, u16* __restrict__ cb)
{
  __shared__ u16 QPs[64*64];                 // Q tile; wave's 16-row slice reused as P
  __shared__ u16 Ks[64*64], Vs[64*64], PBs[64*64];
  __shared__ float Tif[64], Tjf[64];
  const int b = blockIdx.x, it = blockIdx.y, h = blockIdx.z;
  const int i0 = it * 64;
  const int tid = threadIdx.x, wid = tid >> 6, lane = tid & 63;
  const int lr = lane & 15, quad = lane >> 4;
  const int l7 = lane & 7, l3 = lane >> 3;
  const int cc = (l7 ^ l3) * 8;
  const int f8 = lr & 7;
  const int rr = wid*8 + l3;

  const u16* qg  = qb + ((size_t)(b*S_ + i0))*D_ + h*DH_;
  const u16* kg  = kb + ((size_t)b*S_)*D_ + h*DH_;
  const u16* vg  = vt + ((size_t)(b*H_ + h)*DH_)*S_;
  const u16* pbg = pb16 + ((size_t)(h*S_ + i0))*S_;

  gld16(qg + (size_t)rr*D_ + cc,        QPs + wid*512);
  gld16(qg + (size_t)(rr+32)*D_ + cc,   QPs + 2048 + wid*512);
  if (tid < 64) Tif[tid] = (float)ts[b*S_ + i0 + tid] * (1.0f/60000.0f);
  __syncthreads();

  bf16x8 aq0 = *(const bf16x8*)(QPs + (wid*16 + lr)*64 + ((quad ^ f8) * 8));
  bf16x8 aq1 = *(const bf16x8*)(QPs + (wid*16 + lr)*64 + (((quad ^ f8) ^ 4) * 8));
  u16* Pw = QPs + wid*1024;

  float tis[4];
#pragma unroll
  for (int r = 0; r < 4; r++) tis[r] = Tif[wid*16 + quad*4 + r];

  f32x4 O[4]; float lacc[4];
#pragma unroll
  for (int dt = 0; dt < 4; dt++) O[dt] = (f32x4){0.f, 0.f, 0.f, 0.f};
#pragma unroll
  for (int r = 0; r < 4; r++) lacc[r] = 0.f;
  const int lrh = lr >> 3;

  for (int t8 = 0; t8 < 8; t8++) {
    const int j0 = t8 * 64;
    gld16(kg + (size_t)(j0+rr)*D_ + cc,      Ks + wid*512);
    gld16(kg + (size_t)(j0+rr+32)*D_ + cc,   Ks + 2048 + wid*512);
    gld16(vg + (size_t)rr*S_ + j0 + cc,      Vs + wid*512);
    gld16(vg + (size_t)(rr+32)*S_ + j0 + cc, Vs + 2048 + wid*512);
    gld16(pbg + (size_t)rr*S_ + j0 + cc,      PBs + wid*512);
    gld16(pbg + (size_t)(rr+32)*S_ + j0 + cc, PBs + 2048 + wid*512);
    if (tid < 64) Tjf[tid] = (float)ts[b*S_ + j0 + tid] * (1.0f/60000.0f);
    __syncthreads();

    f32x4 s[4];
#pragma unroll
    for (int jt = 0; jt < 4; jt++) {
      const u16* kr = Ks + (jt*16 + lr)*64;
      bf16x8 bk0 = *(const bf16x8*)(kr + ((quad ^ f8) * 8));
      bf16x8 bk1 = *(const bf16x8*)(kr + (((quad ^ f8) ^ 4) * 8));
      f32x4 z = (f32x4){0.f, 0.f, 0.f, 0.f};
      z = mfma16(aq0, bk0, z);
      z = mfma16(aq1, bk1, z);
      s[jt] = z;
    }
#pragma unroll
    for (int r = 0; r < 4; r++) {
      const int rowl = quad*4 + r;
      const int rbase = (wid*16 + rowl) * 64;
      const int r7 = rowl & 7;
      float pa = 0.f;
#pragma unroll
      for (int jt = 0; jt < 4; jt++) {
        const int idx = (((jt*2 + lrh) ^ r7) * 8) + l7;
        float lag = fmaxf(tis[r] - Tjf[idx], 0.0f);
        float inv = (lag + 1.0f) * __builtin_amdgcn_rcpf(fmaf(lag, 9.0f, 8.0f));
        float pbf = b2f(PBs[rbase + idx]);
        float p = __expf(fmaf(s[jt][r], inv, pbf));
        pa += p;
        Pw[rowl*64 + idx] = f2b(p);
      }
      lacc[r] += pa;
    }
    bf16x8 ap0 = *(const bf16x8*)(Pw + lr*64 + ((quad ^ f8) * 8));
    bf16x8 ap1 = *(const bf16x8*)(Pw + lr*64 + (((quad ^ f8) ^ 4) * 8));
#pragma unroll
    for (int dt = 0; dt < 4; dt++) {
      const u16* vr = Vs + (dt*16 + lr)*64;
      bf16x8 bv0 = *(const bf16x8*)(vr + ((quad ^ f8) * 8));
      bf16x8 bv1 = *(const bf16x8*)(vr + (((quad ^ f8) ^ 4) * 8));
      O[dt] = mfma16(ap0, bv0, O[dt]);
      O[dt] = mfma16(ap1, bv1, O[dt]);
    }
    __syncthreads();
  }

#pragma unroll
  for (int r = 0; r < 4; r++) {
    float sum = lacc[r];
#pragma unroll
    for (int m = 1; m < 16; m <<= 1) sum += __shfl_xor(sum, m);
    const float inv = __builtin_amdgcn_rcpf(sum);
    const size_t row = (size_t)(b*S_ + i0 + wid*16 + quad*4 + r);
#pragma unroll
    for (int dt = 0; dt < 4; dt++)
      cb[row*D_ + h*DH_ + dt*16 + lr] = f2b(O[dt][r] * inv);
  }
}

// ---------------- orchestration ---------------------------------------------------
extern "C" void kernel_launch(void* const* d_in, const int* in_sizes, int n_in,
                              void* d_out, int out_size, void* d_ws, size_t ws_size,
                              hipStream_t stream)
{
  const float* hidden = (const float*)d_in[0];
  const float* pbias  = (const float*)d_in[1];
  const int*   ts     = (const int*)d_in[2];
  const float* Wq = (const float*)d_in[3];   const float* bq  = (const float*)d_in[4];
  const float* Wk = (const float*)d_in[5];   const float* bk  = (const float*)d_in[6];
  const float* Wv = (const float*)d_in[7];   const float* bv  = (const float*)d_in[8];
  const float* Wo = (const float*)d_in[9];   const float* bo  = (const float*)d_in[10];
  const float* l1g = (const float*)d_in[11]; const float* l1b = (const float*)d_in[12];
  const float* Wi = (const float*)d_in[13];  const float* bi  = (const float*)d_in[14];
  const float* Wf = (const float*)d_in[15];  const float* bfw = (const float*)d_in[16];
  const float* l2g = (const float*)d_in[17]; const float* l2b = (const float*)d_in[18];

  char* w = (char*)d_ws;
  u16* xb    = (u16*)w; w += (size_t)M_*D_*2;
  u16* qb    = (u16*)w; w += (size_t)M_*D_*2;
  u16* kbuf  = (u16*)w; w += (size_t)M_*D_*2;
  u16* vtw   = (u16*)w; w += (size_t)M_*D_*2;
  u16* cbuf  = (u16*)w; w += (size_t)M_*D_*2;
  u16* attnb = (u16*)w; w += (size_t)M_*D_*2;
  float* yf  = (float*)w; w += (size_t)M_*D_*4;
  u16* WqkvT = (u16*)w; w += (size_t)3*L_*D_*D_*2;
  u16* WoT   = (u16*)w; w += (size_t)L_*D_*D_*2;
  u16* WiT   = (u16*)w; w += (size_t)L_*D_*F_*2;
  u16* WfT   = (u16*)w; w += (size_t)L_*F_*D_*2;
  u16* pbb   = (u16*)w; w += (size_t)H_*S_*S_*2;
  u16* hb    = qb;   // alias: qb..cbuf = M_*F_ bf16; lifetimes disjoint

  float* x = (float*)d_out;   // written only by the final ln2

  const size_t WD = (size_t)D_*D_;
  const size_t WF = (size_t)D_*F_;
  dim3 tb(32, 8);

  transpose_w<<<dim3(16,16,L_), tb, 0, stream>>>(Wq, WqkvT,           D_, D_);
  transpose_w<<<dim3(16,16,L_), tb, 0, stream>>>(Wk, WqkvT + L_*WD,   D_, D_);
  transpose_w<<<dim3(16,16,L_), tb, 0, stream>>>(Wv, WqkvT + 2*L_*WD, D_, D_);
  transpose_w<<<dim3(16,16,L_), tb, 0, stream>>>(Wo, WoT,             D_, D_);
  transpose_w<<<dim3(64,16,L_), tb, 0, stream>>>(Wi, WiT,             D_, F_);
  transpose_w<<<dim3(16,64,L_), tb, 0, stream>>>(Wf, WfT,             F_, D_);
  prep_x<<<dim3(8192), dim3(256), 0, stream>>>(hidden, xb);
  prep_pb<<<dim3(H_*S_*S_/1024), dim3(256), 0, stream>>>(pbias, pbb);

  for (int l = 0; l < L_; l++) {
    gemm_qkv_kernel<<<dim3(128,4,3), dim3(256), 0, stream>>>(
        xb, WqkvT + l*WD, (size_t)L_*WD, D_,
        bq + l*D_, bk + l*D_, bv + l*D_, qb, kbuf, vtw);
    attn_kernel<<<dim3(B_,8,H_), dim3(256), 0, stream>>>(qb, kbuf, vtw, pbb, ts, cbuf);
    gemm64_kernel<<<dim3(256,4), dim3(256), 0, stream>>>(
        cbuf, WoT + l*WD, D_, D_, bo + l*D_, xb, yf);
    ln_kernel<<<dim3(4096), dim3(256), 0, stream>>>(yf, l1g + l*D_, l1b + l*D_,
                                                    (float*)nullptr, attnb);
    gemm_kernel<<<dim3(128,16), dim3(256), 0, stream>>>(
        attnb, WiT + l*WF, F_, D_, bi + l*F_, hb, 2);
    gemm64_kernel<<<dim3(256,4), dim3(256), 0, stream>>>(
        hb, WfT + l*WF, D_, F_, bfw + l*D_, attnb, yf);
    ln_kernel<<<dim3(4096), dim3(256), 0, stream>>>(yf, l2g + l*D_, l2b + l*D_,
                                                    (l == 3) ? x : (float*)nullptr, xb);
  }
}